// Round 10
// baseline (137.171 us; speedup 1.0000x reference)
//
#include <hip/hip_runtime.h>

#define FEAT    4096
#define NACT    512
#define THREADS 256
#define GSZ     128             // threads per row-group (2 waves)
#define NG      2               // independent row-groups per block
#define CHUNKS  8               // float4 chunks per group-thread: 8*128*4 = 4096
#define KRANK   (FEAT - NACT)   // 3584: ascending rank of smallest kept elem
#define FLO     0.8f
#define FHI     1.5f
#define RBINS   1024
#define HIBIN   1024            // physical slot counting x with bin >= RBINS
#define BUFW    1040            // per-group buf words (1024 swizzled + hi + pad)
#define MAXCAND 64

// Order-preserving float32 <-> uint32 key transform (fallback path only).
__device__ __forceinline__ unsigned f2key(float f) {
    unsigned b = __float_as_uint(f);
    return (b & 0x80000000u) ? ~b : (b | 0x80000000u);
}
__device__ __forceinline__ float key2f(unsigned k) {
    unsigned b = (k & 0x80000000u) ? (k & 0x7fffffffu) : ~k;
    return __uint_as_float(b);
}

// NOTE (R7-R9 lessons): do NOT hold the row in a register array — the compiler
// reloads from cache anyway (R9: VGPR=64 + scratch). Streaming reloads keep
// VGPR ~R5's 32-48, so (256,8) is safe. Do NOT use 64-thread blocks (R7:
// wg-slot cliff, 35% occupancy).
__global__ __launch_bounds__(THREADS, 8) void normactive_kernel(
        const float* __restrict__ in, float* __restrict__ out, int batch) {
    const int tid  = threadIdx.x;
    const int rid  = tid >> 7;            // row-group id within block (0/1)
    const int g    = tid & (GSZ - 1);     // thread index within group
    const int wig  = g >> 6;              // wave index within group (0/1)
    const int lane = tid & 63;

    int row = blockIdx.x * NG + rid;
    if (row >= batch) row = batch - 1;    // duplicate last row: benign identical writes
    const float* rp = in  + (size_t)row * FEAT;
    float*       op = out + (size_t)row * FEAT;

    __shared__ __align__(16) unsigned buf[NG][BUFW];                // 8.3 KB
    __shared__ __align__(16) unsigned long long cand[NG][MAXCAND];  // 1 KB
    __shared__ unsigned wsum[NG][2];
    __shared__ unsigned s_B[NG], s_kk[NG], s_cnt[NG], s_n[NG], s_f[NG];
    __shared__ float s_vb[NG];
    __shared__ int   s_ti[NG];
    __shared__ int   s_fb;                // any-group-needs-fallback flag

    unsigned* const mybuf = buf[rid];

    // ---- Zero both groups' histograms + counters (2080 words = 520 uint4).
    uint4 z; z.x = z.y = z.z = z.w = 0u;
    {
        uint4* bz = reinterpret_cast<uint4*>(&buf[0][0]);
        bz[tid] = z; bz[tid + 256] = z;
        if (tid < 8) bz[tid + 512] = z;
        if (tid < NG) s_n[tid] = 0u;
        if (tid == 0) s_fb = 0;
    }
    __syncthreads();

    // ---- Classify: histogram x>FLO into 1024 value bins, overflow bin = HIBIN.
    // Swizzle: bin b (b<1024) -> slot (b>>3) | ((b&7)<<7), so thread g's later
    // scan reads (bins 8g..8g+7 at slots g + 128*i) are lane-consecutive.
    const float invw = (float)RBINS / (FHI - FLO);
    #pragma unroll
    for (int c = 0; c < CHUNKS; ++c) {
        float4 t4 = reinterpret_cast<const float4*>(rp)[c * GSZ + g];
        float xs[4] = {t4.x, t4.y, t4.z, t4.w};
        #pragma unroll
        for (int j = 0; j < 4; ++j) {
            float x = xs[j];
            if (x > FLO) {
                int bi = (int)((x - FLO) * invw);   // monotone in x; cvt saturates
                unsigned slot = (bi >= RBINS) ? (unsigned)HIBIN
                              : (((unsigned)bi >> 3) | (((unsigned)bi & 7u) << 7));
                atomicAdd(&mybuf[slot], 1u);
            }
        }
    }
    __syncthreads();

    // ---- Scan: thread g owns bins [8g, 8g+8); 2-wave scan per group.
    unsigned csum = 0;
    #pragma unroll
    for (int i = 0; i < 8; ++i)
        csum += mybuf[g + (i << 7)];
    unsigned incl = csum;
    #pragma unroll
    for (int off = 1; off < 64; off <<= 1) {
        unsigned n = __shfl_up(incl, (unsigned)off, 64);
        if (lane >= off) incl += n;
    }
    if (lane == 63) wsum[rid][wig] = incl;
    __syncthreads();
    const unsigned nIn  = wsum[rid][0] + wsum[rid][1];
    const unsigned excl = (wig ? wsum[rid][0] : 0u) + incl - csum;
    const int nHi = (int)mybuf[HIBIN];
    const int nLo = FEAT - (int)nIn - nHi;
    const int kkb = KRANK - nLo;          // asc rank of boundary within binned region

    const bool mode0 = (kkb >= 0 && kkb < (int)nIn);
    if (!mode0 && g == 0) s_fb = 1;

    // ---- Rank-find: locate the boundary bin (exactly one thread hits).
    if (mode0) {
        unsigned run = excl;
        #pragma unroll
        for (int i = 0; i < 8; ++i) {
            unsigned ci = mybuf[g + (i << 7)];
            if ((unsigned)kkb >= run && (unsigned)kkb < run + ci) {
                s_B[rid]   = (unsigned)(8 * g + i);
                s_kk[rid]  = (unsigned)kkb - run;
                s_cnt[rid] = ci;
            }
            run += ci;
        }
    }
    __syncthreads();
    if (mode0 && g == 0 && s_cnt[rid] > MAXCAND) s_fb = 1;
    __syncthreads();
    const bool fb = (s_fb != 0);          // block-uniform branch (barrier safety)

    float vb; int ti;
    if (!fb) {
        const unsigned Bv = s_B[rid], kkv = s_kk[rid], cntv = s_cnt[rid];
        // ---- Compact boundary-bin candidates as (bits<<32)|idx (values >FLO>0,
        // so uint-bit order == float order; (value,idx) == stable-sort tie rule).
        #pragma unroll
        for (int c = 0; c < CHUNKS; ++c) {
            float4 t4 = reinterpret_cast<const float4*>(rp)[c * GSZ + g];
            float xs[4] = {t4.x, t4.y, t4.z, t4.w};
            #pragma unroll
            for (int j = 0; j < 4; ++j) {
                float x = xs[j];
                if (x > FLO) {
                    int bi = (int)((x - FLO) * invw);
                    if ((unsigned)bi == Bv) {
                        unsigned idx = (unsigned)(c * 512 + g * 4 + j);
                        unsigned pos = atomicAdd(&s_n[rid], 1u);
                        cand[rid][pos] = ((unsigned long long)__float_as_uint(x) << 32) | idx;
                    }
                }
            }
        }
        __syncthreads();
        if (g < (int)cntv) {
            unsigned long long my = cand[rid][g];
            unsigned r = 0;
            for (unsigned j2 = 0; j2 < cntv; ++j2)
                r += (cand[rid][j2] < my) ? 1u : 0u;
            if (r == kkv) {               // exactly one thread per group
                s_vb[rid] = __uint_as_float((unsigned)(my >> 32));
                s_ti[rid] = (int)(my & 0xffffffffu);
            }
        }
        __syncthreads();
        vb = s_vb[rid]; ti = s_ti[rid];
    } else {
        // ---- Generic exact fallback (never taken for this input); both groups
        // run it in lockstep (fixed barrier counts). 4-pass 8-bit radix select.
        unsigned prefix = 0, kk = (unsigned)KRANK, nEq = 0;
        for (int pass = 0; pass < 4; ++pass) {
            const int shift = 24 - 8 * pass;
            if (g < 64) reinterpret_cast<uint4*>(mybuf)[g] = z;   // zero 256 bins
            __syncthreads();
            for (int c = 0; c < CHUNKS; ++c) {
                float4 t4 = reinterpret_cast<const float4*>(rp)[c * GSZ + g];
                float xs[4] = {t4.x, t4.y, t4.z, t4.w};
                for (int j = 0; j < 4; ++j) {
                    unsigned k = f2key(xs[j]);
                    bool cp = (pass == 0) || ((k >> (shift + 8)) == prefix);
                    if (cp) atomicAdd(&mybuf[(k >> shift) & 255u], 1u);
                }
            }
            __syncthreads();
            if (g == 0) {
                unsigned run = 0;
                for (int d = 0; d < 256; ++d) {
                    unsigned ci = mybuf[d];
                    if (kk < run + ci) { s_B[rid] = (unsigned)d; s_kk[rid] = kk - run; s_cnt[rid] = ci; break; }
                    run += ci;
                }
            }
            __syncthreads();
            prefix = (prefix << 8) | s_B[rid];
            kk  = s_kk[rid];
            nEq = s_cnt[rid];
            __syncthreads();
        }
        const unsigned K = prefix;
        const unsigned kEq = nEq - kk;    // #(==K) to keep, largest indices
        int lo = 0, hi2 = FEAT;
        for (int it = 0; it < 13; ++it) { // fixed-trip: barrier-uniform
            int mid = (lo + hi2 + 1) >> 1;
            if (g == 0) s_f[rid] = 0u;
            __syncthreads();
            unsigned cnt2 = 0;
            for (int c = 0; c < CHUNKS; ++c) {
                float4 t4 = reinterpret_cast<const float4*>(rp)[c * GSZ + g];
                float xs[4] = {t4.x, t4.y, t4.z, t4.w};
                for (int j = 0; j < 4; ++j) {
                    int idx = c * 512 + g * 4 + j;
                    if (f2key(xs[j]) == K && idx >= mid) ++cnt2;
                }
            }
            if (cnt2) atomicAdd(&s_f[rid], cnt2);
            __syncthreads();
            if (s_f[rid] >= kEq) lo = mid; else hi2 = mid - 1;
            __syncthreads();
        }
        vb = key2f(K);
        ti = lo;
    }

    // ---- Output: keep iff x > vb, or x == vb with idx >= ti. Exact x8 scale.
    #pragma unroll
    for (int c = 0; c < CHUNKS; ++c) {
        float4 t4 = reinterpret_cast<const float4*>(rp)[c * GSZ + g];
        const int base = c * 512 + g * 4;
        float4 o;
        o.x = (t4.x > vb || (t4.x == vb && base + 0 >= ti)) ? t4.x * 8.0f : 0.0f;
        o.y = (t4.y > vb || (t4.y == vb && base + 1 >= ti)) ? t4.y * 8.0f : 0.0f;
        o.z = (t4.z > vb || (t4.z == vb && base + 2 >= ti)) ? t4.z * 8.0f : 0.0f;
        o.w = (t4.w > vb || (t4.w == vb && base + 3 >= ti)) ? t4.w * 8.0f : 0.0f;
        reinterpret_cast<float4*>(op)[c * GSZ + g] = o;
    }
}

extern "C" void kernel_launch(void* const* d_in, const int* in_sizes, int n_in,
                              void* d_out, int out_size, void* d_ws, size_t ws_size,
                              hipStream_t stream) {
    const float* feat = (const float*)d_in[0];
    float* out = (float*)d_out;
    const int batch = in_sizes[0] / FEAT;  // 8192
    const int nblk = (batch + NG - 1) / NG;
    normactive_kernel<<<nblk, THREADS, 0, stream>>>(feat, out, batch);
}

// Round 11
// 63.545 us; speedup vs baseline: 2.1586x; 2.1586x over previous
//
#include <hip/hip_runtime.h>

#define FEAT    4096
#define NACT    512
#define THREADS 256
#define GSZ     128             // threads per row-group (2 waves)
#define NG      2               // independent row-groups per block
#define CHUNKS  8               // float4 chunks per group-thread: 8*128*4 = 4096
#define KRANK   (FEAT - NACT)   // 3584: ascending rank of smallest kept elem
#define FLO     0.8f
#define FHI     1.5f
#define RBINS   1024
#define HIBIN   1024            // physical slot counting bin >= RBINS
#define BUFW    1040            // per-group buf words (1024 swizzled + hi + pad)
#define MAXCAND 64

typedef unsigned long long ull;

// Launder a pointer so the compiler cannot CSE loads across passes.
// R10 lesson: const __restrict__ + repeated reads => compiler merges the
// passes into a ~32-float live range and SPILLS under the VGPR cap.
#define LAUNDER(p) asm volatile("" : "+v"(p) :: "memory")

// Order-preserving float32 <-> uint32 key transform (fallback path only).
__device__ __forceinline__ unsigned f2key(float f) {
    unsigned b = __float_as_uint(f);
    return (b & 0x80000000u) ? ~b : (b | 0x80000000u);
}
__device__ __forceinline__ float key2f(unsigned k) {
    unsigned b = (k & 0x80000000u) ? (k & 0x7fffffffu) : ~k;
    return __uint_as_float(b);
}

__global__ __launch_bounds__(THREADS, 8) void normactive_kernel(
        const float* __restrict__ in, float* __restrict__ out, int batch) {
    const int tid  = threadIdx.x;
    const int rid  = tid >> 7;            // row-group id within block (0/1)
    const int g    = tid & (GSZ - 1);     // thread index within group
    const int wig  = g >> 6;              // wave index within group (0/1)
    const int lane = tid & 63;

    int row = blockIdx.x * NG + rid;
    if (row >= batch) row = batch - 1;    // benign duplicate (exact div anyway)
    const float* rp = in  + (size_t)row * FEAT;
    float*       op = out + (size_t)row * FEAT;

    __shared__ __align__(16) unsigned buf[NG][BUFW];        // 8.3 KB
    __shared__ __align__(16) ull cand[NG][MAXCAND];         // 1 KB
    __shared__ unsigned wsum[NG][2];
    __shared__ unsigned s_B[NG], s_kk[NG], s_cnt[NG], s_n[NG], s_f[NG];
    __shared__ float s_vb[NG];
    __shared__ int   s_ti[NG];
    __shared__ int   s_fb;

    unsigned* const mybuf = buf[rid];

    // ---- Zero both groups' histograms + counters (2080 words = 520 uint4).
    uint4 z; z.x = z.y = z.z = z.w = 0u;
    {
        uint4* bz = reinterpret_cast<uint4*>(&buf[0][0]);
        bz[tid] = z; bz[tid + 256] = z;
        if (tid < 8) bz[tid + 512] = z;
        if (tid < NG) s_n[tid] = 0u;
        if (tid == 0) s_fb = 0;
    }
    __syncthreads();

    // ---- PASS 1: histogram x>FLO into 1024 value bins (+ overflow bin).
    // Swizzle: bin b -> slot (b>>3)|((b&7)<<7): thread g's scan reads
    // (bins 8g..8g+7 at slots g + 128*i) are lane-consecutive.
    const float invw = (float)RBINS / (FHI - FLO);
    {
        const float4* rp4 = reinterpret_cast<const float4*>(rp);
        #pragma unroll 4
        for (int c = 0; c < CHUNKS; ++c) {
            float4 t4 = rp4[c * GSZ + g];
            #define CLS(X) { float _x = (X); if (_x > FLO) {                        \
                int bi = (int)((_x - FLO) * invw);                                   \
                unsigned slot = (bi >= RBINS) ? (unsigned)HIBIN                      \
                    : (((unsigned)bi >> 3) | (((unsigned)bi & 7u) << 7));            \
                atomicAdd(&mybuf[slot], 1u); } }
            CLS(t4.x) CLS(t4.y) CLS(t4.z) CLS(t4.w)
            #undef CLS
        }
    }
    __syncthreads();

    // ---- Scan: thread g owns bins [8g, 8g+8); 2-wave scan per group.
    unsigned csum = 0;
    #pragma unroll
    for (int i = 0; i < 8; ++i)
        csum += mybuf[g + (i << 7)];
    unsigned incl = csum;
    #pragma unroll
    for (int off = 1; off < 64; off <<= 1) {
        unsigned n = __shfl_up(incl, (unsigned)off, 64);
        if (lane >= off) incl += n;
    }
    if (lane == 63) wsum[rid][wig] = incl;
    __syncthreads();
    const unsigned nIn  = wsum[rid][0] + wsum[rid][1];
    const unsigned excl = (wig ? wsum[rid][0] : 0u) + incl - csum;
    const int nHi = (int)mybuf[HIBIN];
    const int nLo = FEAT - (int)nIn - nHi;
    const int kkb = KRANK - nLo;          // asc rank of boundary within binned region

    const bool mode0 = (kkb >= 0 && kkb < (int)nIn);
    if (!mode0 && g == 0) s_fb = 1;

    if (mode0) {                          // exactly one thread per group hits
        unsigned run = excl;
        #pragma unroll
        for (int i = 0; i < 8; ++i) {
            unsigned ci = mybuf[g + (i << 7)];
            if ((unsigned)kkb >= run && (unsigned)kkb < run + ci) {
                s_B[rid]   = (unsigned)(8 * g + i);
                s_kk[rid]  = (unsigned)kkb - run;
                s_cnt[rid] = ci;
            }
            run += ci;
        }
    }
    __syncthreads();
    if (mode0 && g == 0 && s_cnt[rid] > MAXCAND) s_fb = 1;
    __syncthreads();
    const bool fb = (s_fb != 0);          // block-uniform

    if (!fb) {
        const unsigned Bv = s_B[rid];
        // ---- PASS 2 (fused output + compact): non-boundary elements need only
        // their BIN vs Bv (keep <=> bin > Bv); boundary-bin elements get a
        // provisional 0 and are compacted as (bits<<32)|idx for the epilogue.
        const float4* rp4 = reinterpret_cast<const float4*>(rp);
        LAUNDER(rp4);                     // forbid CSE with pass 1
        #pragma unroll 4
        for (int c = 0; c < CHUNKS; ++c) {
            float4 t4 = rp4[c * GSZ + g];
            const int base = c * 512 + g * 4;
            float4 o;
            #define OUTJ(X, OJ, JJ) { float _x = (X);                                \
                bool inr = (_x > FLO);                                               \
                int bi = (int)((_x - FLO) * invw);                                   \
                if (inr && (unsigned)bi == Bv) {                                     \
                    unsigned pos = atomicAdd(&s_n[rid], 1u);                         \
                    cand[rid][pos] = ((ull)__float_as_uint(_x) << 32)                \
                                     | (unsigned)(base + JJ);                        \
                }                                                                    \
                OJ = (inr && bi > (int)Bv) ? _x * 8.0f : 0.0f; }
            OUTJ(t4.x, o.x, 0) OUTJ(t4.y, o.y, 1) OUTJ(t4.z, o.z, 2) OUTJ(t4.w, o.w, 3)
            #undef OUTJ
            reinterpret_cast<float4*>(op)[c * GSZ + g] = o;
        }
        __syncthreads();                  // cand[] + s_n visible; stores drained

        // ---- Epilogue: among boundary-bin candidates keep in-bin (value,idx)
        // ranks >= kk (largest indices win ties == stable-argsort tail rule).
        const unsigned cntv = s_cnt[rid], kkv = s_kk[rid];
        if (g < (int)cntv) {
            ull my = cand[rid][g];
            unsigned r = 0;
            for (unsigned j = 0; j < cntv; ++j)
                r += (cand[rid][j] < my) ? 1u : 0u;
            if (r >= kkv) {
                unsigned idx = (unsigned)(my & 0xffffffffu);
                op[idx] = __uint_as_float((unsigned)(my >> 32)) * 8.0f;
            }
        }
    } else {
        // ---- Generic exact fallback (never taken for this input); block-
        // uniform, fixed barrier counts. 4-pass 8-bit radix select + tie search.
        const float4* rp4 = reinterpret_cast<const float4*>(rp);
        LAUNDER(rp4);
        uint4 zz; zz.x = zz.y = zz.z = zz.w = 0u;
        unsigned prefix = 0, kk = (unsigned)KRANK, nEq = 0;
        for (int pass = 0; pass < 4; ++pass) {
            const int shift = 24 - 8 * pass;
            if (g < 64) reinterpret_cast<uint4*>(mybuf)[g] = zz;
            __syncthreads();
            for (int c = 0; c < CHUNKS; ++c) {
                float4 t4 = rp4[c * GSZ + g];
                #define HST(X) { unsigned k = f2key(X);                              \
                    bool cp = (pass == 0) || ((k >> (shift + 8)) == prefix);         \
                    if (cp) atomicAdd(&mybuf[(k >> shift) & 255u], 1u); }
                HST(t4.x) HST(t4.y) HST(t4.z) HST(t4.w)
                #undef HST
            }
            __syncthreads();
            if (g == 0) {
                unsigned run = 0;
                for (int d = 0; d < 256; ++d) {
                    unsigned ci = mybuf[d];
                    if (kk < run + ci) { s_B[rid] = (unsigned)d; s_kk[rid] = kk - run; s_cnt[rid] = ci; break; }
                    run += ci;
                }
            }
            __syncthreads();
            prefix = (prefix << 8) | s_B[rid];
            kk  = s_kk[rid];
            nEq = s_cnt[rid];
            __syncthreads();
        }
        const unsigned K = prefix;
        const unsigned kEq = nEq - kk;    // #(==K) kept, largest indices
        int lo = 0, hi2 = FEAT;
        for (int it = 0; it < 13; ++it) { // fixed-trip: barrier-uniform
            int mid = (lo + hi2 + 1) >> 1;
            if (g == 0) s_f[rid] = 0u;
            __syncthreads();
            unsigned cnt2 = 0;
            for (int c = 0; c < CHUNKS; ++c) {
                float4 t4 = rp4[c * GSZ + g];
                const int base = c * 512 + g * 4;
                #define TST(X, JJ) { if (f2key(X) == K && base + JJ >= mid) ++cnt2; }
                TST(t4.x, 0) TST(t4.y, 1) TST(t4.z, 2) TST(t4.w, 3)
                #undef TST
            }
            if (cnt2) atomicAdd(&s_f[rid], cnt2);
            __syncthreads();
            if (s_f[rid] >= kEq) lo = mid; else hi2 = mid - 1;
            __syncthreads();
        }
        const float vb = key2f(K);
        const int   ti = lo;
        for (int c = 0; c < CHUNKS; ++c) {
            float4 t4 = rp4[c * GSZ + g];
            const int base = c * 512 + g * 4;
            float4 o;
            o.x = (t4.x > vb || (t4.x == vb && base + 0 >= ti)) ? t4.x * 8.0f : 0.0f;
            o.y = (t4.y > vb || (t4.y == vb && base + 1 >= ti)) ? t4.y * 8.0f : 0.0f;
            o.z = (t4.z > vb || (t4.z == vb && base + 2 >= ti)) ? t4.z * 8.0f : 0.0f;
            o.w = (t4.w > vb || (t4.w == vb && base + 3 >= ti)) ? t4.w * 8.0f : 0.0f;
            reinterpret_cast<float4*>(op)[c * GSZ + g] = o;
        }
    }
}

extern "C" void kernel_launch(void* const* d_in, const int* in_sizes, int n_in,
                              void* d_out, int out_size, void* d_ws, size_t ws_size,
                              hipStream_t stream) {
    const float* feat = (const float*)d_in[0];
    float* out = (float*)d_out;
    const int batch = in_sizes[0] / FEAT;  // 8192
    const int nblk = (batch + NG - 1) / NG;
    normactive_kernel<<<nblk, THREADS, 0, stream>>>(feat, out, batch);
}

// Round 12
// 44.927 us; speedup vs baseline: 3.0532x; 1.4144x over previous
//
#include <hip/hip_runtime.h>

#define FEAT    4096
#define NACT    512
#define THREADS 256
#define EPT     16
#define KRANK   (FEAT - NACT)   // 3584: ascending rank of smallest kept elem
#define FLO     0.8f
#define FHI     1.5f
#define RBINS   1024
#define MAXCAND 64

// Order-preserving float32 <-> uint32 key transform (fallback path only).
__device__ __forceinline__ unsigned f2key(float f) {
    unsigned b = __float_as_uint(f);
    return (b & 0x80000000u) ? ~b : (b | 0x80000000u);
}
__device__ __forceinline__ float key2f(unsigned k) {
    unsigned b = (k & 0x80000000u) ? (k & 0x7fffffffu) : ~k;
    return __uint_as_float(b);
}

// R5 structure — proven best (45.6 us). R6 (NT stores), R7 (64-thread blocks),
// R8/R9 (wave-private rows, reg-resident xv[64]), R10/R11 (2 rows/block,
// streaming re-reads) ALL regressed: 47.1 / 55.2 / 187 / 60.0 / 137 / 63.5 us.
// Keys: 1 row per 256-thread block; xv[16] (VGPR=32, no spill); one global
// read; ~6 barriers; 1024-bin value-range histogram on (0.8, 1.5].
__global__ __launch_bounds__(THREADS, 8) void normactive_kernel(
        const float* __restrict__ in, float* __restrict__ out) {
    const int tid  = threadIdx.x;
    const int wid  = tid >> 6;
    const int lane = tid & 63;
    const float* rp = in  + (size_t)blockIdx.x * FEAT;
    float*       op = out + (size_t)blockIdx.x * FEAT;

    __shared__ __align__(16) unsigned buf[4096];   // 1024-bin range hist; fallback 4096-bin hist + compact
    __shared__ unsigned long long cand[MAXCAND];
    __shared__ unsigned wsum[4];
    __shared__ unsigned s_nhi, s_n, s_B, s_kk, s_cnt, s_tidx;
    __shared__ float s_vb;

    // ---- Load row into registers (coalesced float4).
    float xv[EPT];
    #pragma unroll
    for (int c = 0; c < 4; ++c) {
        float4 t = reinterpret_cast<const float4*>(rp)[c * THREADS + tid];
        xv[4*c+0] = t.x; xv[4*c+1] = t.y; xv[4*c+2] = t.z; xv[4*c+3] = t.w;
    }

    // ---- Zero 1024-bin histogram + counters.
    uint4 z; z.x = z.y = z.z = z.w = 0u;
    reinterpret_cast<uint4*>(buf)[tid] = z;        // 256 * 16B = 1024 words
    if (tid == 0) { s_nhi = 0; s_n = 0; }
    __syncthreads();

    // ---- Classify: count x > FHI; histogram x in (FLO, FHI] into 1024 bins.
    const float invw = (float)RBINS / (FHI - FLO);
    unsigned chi = 0;
    unsigned ub[EPT];                              // per-element bin (0xffffffff = not in range)
    #pragma unroll
    for (int e = 0; e < EPT; ++e) {
        float x = xv[e];
        bool hi = (x > FHI);
        chi += hi ? 1u : 0u;
        unsigned b = 0xffffffffu;
        if (x > FLO && !hi) {
            int bi = (int)((x - FLO) * invw);      // >= 0 since x > FLO; monotone in x
            bi = bi < (RBINS - 1) ? bi : (RBINS - 1);
            b = (unsigned)bi;
            atomicAdd(&buf[bi], 1u);
        }
        ub[e] = b;
    }
    #pragma unroll
    for (int off = 32; off >= 1; off >>= 1)
        chi += __shfl_xor(chi, (unsigned)off, 64);
    if (lane == 0) atomicAdd(&s_nhi, chi);
    __syncthreads();

    const int nHi = (int)s_nhi;

    // ---- Scan: thread t owns bins [4t, 4t+4); one b128 read + wave scan.
    uint4 q = reinterpret_cast<const uint4*>(buf)[tid];
    unsigned s = q.x + q.y + q.z + q.w;
    unsigned inc = s;
    #pragma unroll
    for (int off = 1; off < 64; off <<= 1) {
        unsigned n = __shfl_up(inc, (unsigned)off, 64);
        if (lane >= off) inc += n;
    }
    if (lane == 63) wsum[wid] = inc;
    __syncthreads();
    unsigned base = 0;
    #pragma unroll
    for (int w = 0; w < 3; ++w) if (w < wid) base += wsum[w];
    const int nIn = (int)(wsum[0] + wsum[1] + wsum[2] + wsum[3]);
    const unsigned excl = base + inc - s;          // asc prefix at bin 4*tid (within range region)

    const int nLo  = FEAT - nIn - nHi;
    const int need = NACT - nHi;                   // kept elements still needed from binned region
    const int kkb  = KRANK - nLo;                  // asc rank of boundary within binned region

    // mode: 0 = boundary in an interior bin, 1 = threshold exactly at FHI, 2 = generic fallback
    int mode = (need > 0 && kkb >= 0 && kkb < nIn) ? 0 : ((need == 0) ? 1 : 2);

    if (mode == 0) {
        unsigned bq[4] = {q.x, q.y, q.z, q.w};
        unsigned run = excl;
        #pragma unroll
        for (int i = 0; i < 4; ++i) {
            if ((unsigned)kkb >= run && (unsigned)kkb < run + bq[i]) {
                s_B   = (unsigned)(4 * tid + i);
                s_kk  = (unsigned)kkb - run;
                s_cnt = bq[i];
            }
            run += bq[i];
        }
    }
    __syncthreads();

    if (mode == 0 && s_cnt > MAXCAND) mode = 2;    // uniform

    if (mode == 0) {
        const unsigned B = s_B, kk = s_kk, cnt = s_cnt;
        // Compact boundary-bin candidates as (bits, idx); all in-range values are
        // positive so uint-bit order == float order. (value, idx) lexicographic
        // == reference stable-sort tie rule (largest indices kept).
        #pragma unroll
        for (int e = 0; e < EPT; ++e) {
            if (ub[e] == B) {
                unsigned idx = (unsigned)((e >> 2) * 1024 + tid * 4 + (e & 3));
                unsigned pos = atomicAdd(&s_n, 1u);
                cand[pos] = ((unsigned long long)__float_as_uint(xv[e]) << 32) | idx;
            }
        }
        __syncthreads();
        if (tid < (int)cnt) {
            unsigned long long my = cand[tid];
            unsigned r = 0;
            for (unsigned j = 0; j < cnt; ++j) r += (cand[j] < my) ? 1u : 0u;
            if (r == kk) {                          // exactly one thread matches
                s_vb   = __uint_as_float((unsigned)(my >> 32));
                s_tidx = (unsigned)(my & 0xffffffffu);
            }
        }
    } else if (mode == 1) {
        // Exactly nHi == 512: keep = (x > FHI); no ties kept.
        if (tid == 0) { s_vb = FHI; s_tidx = (unsigned)FEAT; }
    } else {
        // ---- Generic fallback (never taken for this input): 12-bit key hist +
        // compact + rank-select. Keys recomputed inline from xv (no extra VGPR).
        #pragma unroll
        for (int i = 0; i < 4; ++i)
            reinterpret_cast<uint4*>(buf)[i * THREADS + tid] = z;
        if (tid == 0) s_n = 0;
        __syncthreads();
        #pragma unroll
        for (int e = 0; e < EPT; ++e)
            atomicAdd(&buf[f2key(xv[e]) >> 20], 1u);
        __syncthreads();
        unsigned tot = 0;
        #pragma unroll
        for (int i = 0; i < 16; ++i) tot += buf[16 * tid + i];
        unsigned inc2 = tot;
        #pragma unroll
        for (int off = 1; off < 64; off <<= 1) {
            unsigned n = __shfl_up(inc2, (unsigned)off, 64);
            if (lane >= off) inc2 += n;
        }
        if (lane == 63) wsum[wid] = inc2;
        __syncthreads();
        unsigned b2 = 0;
        #pragma unroll
        for (int w = 0; w < 3; ++w) if (w < wid) b2 += wsum[w];
        unsigned ex2 = b2 + inc2 - tot;
        if ((unsigned)KRANK >= ex2 && (unsigned)KRANK < ex2 + tot) {
            unsigned run = ex2;
            #pragma unroll
            for (int i = 0; i < 16; ++i) {
                unsigned c = buf[16 * tid + i];
                if ((unsigned)KRANK >= run && (unsigned)KRANK < run + c) {
                    s_B   = (unsigned)(16 * tid + i);
                    s_kk  = (unsigned)KRANK - run;
                    s_cnt = c;
                }
                run += c;
            }
        }
        __syncthreads();
        const unsigned P = s_B, kk2 = s_kk, cnt2 = s_cnt;
        #pragma unroll
        for (int e = 0; e < EPT; ++e) {
            unsigned k = f2key(xv[e]);
            if ((k >> 20) == P) {
                unsigned idx = (unsigned)((e >> 2) * 1024 + tid * 4 + (e & 3));
                unsigned pos = atomicAdd(&s_n, 1u);
                buf[pos] = (k << 12) | idx;
            }
        }
        __syncthreads();
        for (unsigned slot = tid; slot < cnt2; slot += THREADS) {
            unsigned my = buf[slot];
            unsigned r = 0;
            for (unsigned j = 0; j < cnt2; ++j) r += (buf[j] < my) ? 1u : 0u;
            if (r == kk2) {
                s_vb   = key2f((P << 20) | (my >> 12));   // candidates share top-12 bits P
                s_tidx = my & 0xfffu;
            }
        }
    }
    __syncthreads();

    const float vb = s_vb;
    const int   ti = (int)s_tidx;

    // ---- Output: keep iff x > vb, or x == vb with idx >= ti. Exact x8 scale.
    #pragma unroll
    for (int c = 0; c < 4; ++c) {
        const int bidx = c * 1024 + tid * 4;
        float a0 = xv[4*c+0], a1 = xv[4*c+1], a2 = xv[4*c+2], a3 = xv[4*c+3];
        float4 o;
        o.x = (a0 > vb || (a0 == vb && bidx + 0 >= ti)) ? a0 * 8.0f : 0.0f;
        o.y = (a1 > vb || (a1 == vb && bidx + 1 >= ti)) ? a1 * 8.0f : 0.0f;
        o.z = (a2 > vb || (a2 == vb && bidx + 2 >= ti)) ? a2 * 8.0f : 0.0f;
        o.w = (a3 > vb || (a3 == vb && bidx + 3 >= ti)) ? a3 * 8.0f : 0.0f;
        reinterpret_cast<float4*>(op)[c * THREADS + tid] = o;
    }
}

extern "C" void kernel_launch(void* const* d_in, const int* in_sizes, int n_in,
                              void* d_out, int out_size, void* d_ws, size_t ws_size,
                              hipStream_t stream) {
    const float* feat = (const float*)d_in[0];
    float* out = (float*)d_out;
    const int batch = in_sizes[0] / FEAT;  // 8192
    normactive_kernel<<<batch, THREADS, 0, stream>>>(feat, out);
}